// Round 14
// baseline (292.388 us; speedup 1.0000x reference)
//
#include <hip/hip_runtime.h>
#include <hip/hip_bf16.h>
#include <hip/hip_fp8.h>
#include <math.h>

#define NEG (-1.0e9f)

typedef __bf16 bf16_t;
typedef __bf16 bf16x4 __attribute__((ext_vector_type(4)));
typedef __bf16 bf16x8 __attribute__((ext_vector_type(8)));
typedef float f32x2 __attribute__((ext_vector_type(2)));
typedef float f32x4 __attribute__((ext_vector_type(4)));
typedef long i64x2 __attribute__((ext_vector_type(2)));
typedef unsigned char u8;
typedef unsigned int u32;
typedef unsigned long long u64;

#define SS 64
#define BB 8
#define HH 512
#define VV 8192
#define NPAIR 1953          /* upper-tri pairs (i<j) over [0,63) */
#define NPTOT 1954          /* + (0,0) row for init_lp */
#define MROWS (NPTOT*BB)    /* 15632 */
#define MPAD  16384         /* 64*256 */

__device__ __forceinline__ float logsig(float x) {
  return fminf(x, 0.f) - __logf(1.f + __expf(-fabsf(x)));
}
__device__ __forceinline__ u8 f2q(float x) { __hip_fp8_e4m3 q(x); return q.__x; }
// k-order permutation within each 64B group: chunk c -> slot 2*(c&3)+(c>>2)
__device__ __forceinline__ int ksl(int c) { return 2 * (c & 3) + (c >> 2); }

// ---------------- preprocessing: h cvt + 2 bf16 transposes ----------------
__global__ __launch_bounds__(256) void k_prep(
    const float* __restrict__ h,   bf16_t* __restrict__ hbf,
    const float* __restrict__ tW1, bf16_t* __restrict__ tW1T,
    const float* __restrict__ wW1, bf16_t* __restrict__ wW1T) {
  __shared__ float tile[32][33];
  int blk = blockIdx.x, tid = threadIdx.x;
  if (blk < 256) {                      // h: 262144 floats, float4-vectorized
    int gi = blk * 256 + tid;
    float4 v = ((const float4*)h)[gi];
    bf16x4 o = {(bf16_t)v.x, (bf16_t)v.y, (bf16_t)v.z, (bf16_t)v.w};
    ((bf16x4*)hbf)[gi] = o;
    return;
  }
  const float* in; bf16_t* out; int R = 1024, C = 512, t;
  if (blk < 768) { in = tW1; out = tW1T; t = blk - 256; }
  else           { in = wW1; out = wW1T; t = blk - 768; }
  int xt = C / 32;
  int c0 = (t % xt) * 32, r0 = (t / xt) * 32;
  int tx = tid & 31, ty = tid >> 5;
  for (int i = ty; i < 32; i += 8)
    tile[i][tx] = in[(size_t)(r0 + i) * C + c0 + tx];
  __syncthreads();
  for (int i = ty; i < 32; i += 8)
    out[(size_t)(c0 + i) * R + r0 + tx] = (bf16_t)tile[tx][i];
}

// ------- fused: 4x small GEMM (blocks 0..63) + wW2->fp8 ksl transpose (blocks 64..4159) ---
__global__ __launch_bounds__(256) void k_gemm4t(
    const bf16_t* __restrict__ A,
    const bf16_t* __restrict__ tW1T, const bf16_t* __restrict__ wW1T,
    float* __restrict__ Ut, float* __restrict__ Vt,
    float* __restrict__ Uw, float* __restrict__ Vw,
    const float* __restrict__ wW2, u8* __restrict__ w2t8)
{
  __shared__ __align__(16) char lds_raw[16384];
  const int tid = threadIdx.x;
  if (blockIdx.x >= 64) {
    float* tile = (float*)lds_raw;      // [32][33]
    int t = blockIdx.x - 64;            // 0..4095
    int c0 = (t % 256) * 32, r0 = (t / 256) * 32;
    int tx = tid & 31, ty = tid >> 5;
    for (int i = ty; i < 32; i += 8)
      tile[i * 33 + tx] = wW2[(size_t)(r0 + i) * 8192 + c0 + tx];
    __syncthreads();
    for (int i = ty; i < 32; i += 8) {
      int k = r0 + tx;
      int pos = (k >> 6) * 64 + ksl((k >> 3) & 7) * 8 + (k & 7);
      w2t8[(size_t)(c0 + i) * 512 + pos] = f2q(tile[tx * 33 + i]);
    }
    return;
  }
  bf16_t* As = (bf16_t*)lds_raw;
  bf16_t* Bs = (bf16_t*)(lds_raw + 8192);
  const int lane = tid & 63;
  const int wave = tid >> 6;
  const int wr = wave >> 1, wc = wave & 1;
  const int sel = blockIdx.x >> 4, sub = blockIdx.x & 15;
  const bf16_t* BT = (sel < 2 ? tW1T : wW1T) + (sel & 1) * 512;
  float* Cout = (sel == 0) ? Ut : (sel == 1) ? Vt : (sel == 2) ? Uw : Vw;
  const int m0 = (sub & 3) * 128, n0 = (sub >> 2) * 128;
  const int lda = 512, ldb = 1024, ldc = 512;

  const int rowS = tid >> 2;
  const int kS = (tid & 3) * 8;
  const bf16_t* gA0 = A + (size_t)(m0 + rowS) * lda + kS;
  const bf16_t* gA1 = A + (size_t)(m0 + rowS + 64) * lda + kS;
  const bf16_t* gB0 = BT + (size_t)(n0 + rowS) * ldb + kS;
  const bf16_t* gB1 = BT + (size_t)(n0 + rowS + 64) * ldb + kS;

  f32x4 acc[4][4] = {};
  const int aoff = (wr * 64 + (lane & 15)) * 32 + (lane >> 4) * 8;
  const int boff = (wc * 64 + (lane & 15)) * 32 + (lane >> 4) * 8;

  for (int k0 = 0; k0 < 512; k0 += 32) {
    __builtin_amdgcn_global_load_lds((const __attribute__((address_space(1))) void*)(gA0 + k0),
        (__attribute__((address_space(3))) void*)(As + wave * 512), 16, 0, 0);
    __builtin_amdgcn_global_load_lds((const __attribute__((address_space(1))) void*)(gA1 + k0),
        (__attribute__((address_space(3))) void*)(As + 2048 + wave * 512), 16, 0, 0);
    __builtin_amdgcn_global_load_lds((const __attribute__((address_space(1))) void*)(gB0 + k0),
        (__attribute__((address_space(3))) void*)(Bs + wave * 512), 16, 0, 0);
    __builtin_amdgcn_global_load_lds((const __attribute__((address_space(1))) void*)(gB1 + k0),
        (__attribute__((address_space(3))) void*)(Bs + 2048 + wave * 512), 16, 0, 0);
    __syncthreads();
    bf16x8 af[4], bfr[4];
    #pragma unroll
    for (int mf = 0; mf < 4; ++mf) af[mf] = *(const bf16x8*)&As[aoff + mf * 16 * 32];
    #pragma unroll
    for (int nf = 0; nf < 4; ++nf) bfr[nf] = *(const bf16x8*)&Bs[boff + nf * 16 * 32];
    #pragma unroll
    for (int mf = 0; mf < 4; ++mf)
      #pragma unroll
      for (int nf = 0; nf < 4; ++nf)
        acc[mf][nf] = __builtin_amdgcn_mfma_f32_16x16x32_bf16(af[mf], bfr[nf], acc[mf][nf], 0, 0, 0);
    __syncthreads();
  }
  #pragma unroll
  for (int mf = 0; mf < 4; ++mf)
    #pragma unroll
    for (int r2 = 0; r2 < 4; ++r2) {
      int grow = m0 + wr * 64 + mf * 16 + (lane >> 4) * 4 + r2;
      #pragma unroll
      for (int nf = 0; nf < 4; ++nf) {
        int gcol = n0 + wc * 64 + nf * 16 + (lane & 15);
        Cout[(size_t)grow * ldc + gcol] = acc[mf][nf][r2];
      }
    }
}

// ---------------- fp8 256x256-tile GEMM, 4-phase/iter (r12-measured: 153.6us, 0 conflicts)
// epilogue: LDS-reduce 4 wc-wave partials -> one plain store per row into psum[nt][row]
#define STAGEA(b, h, kt) do { \
  const u8* _s = A8 + (size_t)(m0 + (h)*128 + (tid>>2)) * 512 + (kt)*64 + csrc; \
  __builtin_amdgcn_global_load_lds((const __attribute__((address_space(1))) void*)_s, \
    (__attribute__((address_space(3))) void*)(As + (b)*16384 + (h)*8192 + (tid>>6)*1024), 16, 0, 0); \
} while(0)

#define STAGEB(b, h, kt) do { \
  const u8* _s = BT8 + (size_t)(n0 + (h)*128 + (tid>>2)) * 512 + (kt)*64 + csrc; \
  __builtin_amdgcn_global_load_lds((const __attribute__((address_space(1))) void*)_s, \
    (__attribute__((address_space(3))) void*)(Bs + (b)*16384 + (h)*8192 + (tid>>6)*1024), 16, 0, 0); \
} while(0)

#define LDA(b, mh) do { \
  _Pragma("unroll") \
  for (int _m = 0; _m < 4; ++_m) \
    afv[_m] = *(const i64x2*)(As + (b)*16384 + (mh)*8192 + ardE + _m*1024); \
} while(0)

#define LDB(b, nh) do { \
  _Pragma("unroll") \
  for (int _n = 0; _n < 2; ++_n) \
    bfv[nh][_n] = *(const i64x2*)(Bs + (b)*16384 + (nh)*8192 + brdE + _n*1024); \
} while(0)

#define MMA(mh, nh) do { \
  __builtin_amdgcn_s_setprio(1); \
  _Pragma("unroll") \
  for (int _m = 0; _m < 4; ++_m) \
    _Pragma("unroll") \
    for (int _n = 0; _n < 2; ++_n) { \
      acc[(mh)*4+_m][(nh)*2+_n] = __builtin_amdgcn_mfma_f32_16x16x32_fp8_fp8( \
          afv[_m][0], bfv[nh][_n][0], acc[(mh)*4+_m][(nh)*2+_n], 0, 0, 0); \
      acc[(mh)*4+_m][(nh)*2+_n] = __builtin_amdgcn_mfma_f32_16x16x32_fp8_fp8( \
          afv[_m][1], bfv[nh][_n][1], acc[(mh)*4+_m][(nh)*2+_n], 0, 0, 0); \
    } \
  __builtin_amdgcn_s_setprio(0); \
} while(0)

#define BARLG() do { __builtin_amdgcn_s_barrier(); \
  asm volatile("s_waitcnt lgkmcnt(0)" ::: "memory"); \
  __builtin_amdgcn_sched_barrier(0); } while(0)
#define ENDPH() __builtin_amdgcn_s_barrier()
#define CKPT() asm volatile("s_waitcnt vmcnt(2)" ::: "memory")

__global__ __launch_bounds__(512, 2) void k_gemm256(
    const u8* __restrict__ A8,
    const u8* __restrict__ BT8,
    const float* __restrict__ bias,
    float* __restrict__ psum)
{
  __shared__ __align__(16) u8 As[2 * 16384];   // [buf][half][128 rows][64B]
  __shared__ __align__(16) u8 Bs[2 * 16384];
  const int tid = threadIdx.x;
  const int l = tid & 63;
  const int wave = tid >> 6;
  const int wr = wave >> 2, wc = wave & 3;   // 2M x 4N waves

  const int xcd = blockIdx.x & 7, sub = blockIdx.x >> 3;   // sub 0..255
  const int mt = xcd * 8 + (sub & 7);
  const int nt = sub >> 3;
  const int m0 = mt * 256, n0 = nt * 256;

  const int csrc = (((tid & 3) ^ ((tid >> 3) & 3)) << 4);
  const int rsw = (((l >> 4) ^ ((l & 15) >> 1)) & 3) << 4;
  const int ardE = (wr * 64 + (l & 15)) * 64 + rsw;
  const int brdE = (wc * 32 + (l & 15)) * 64 + rsw;

  f32x4 acc[8][4] = {};
  i64x2 afv[4];
  i64x2 bfv[2][2];

  // prologue: K-tile 0 -> buf0 full (4 issues); K-tile 1 -> buf1.A0,B0 (2 issues)
  STAGEA(0, 0, 0); STAGEA(0, 1, 0); STAGEB(0, 0, 0); STAGEB(0, 1, 0);
  STAGEA(1, 0, 1); STAGEB(1, 0, 1);
  CKPT();
  __builtin_amdgcn_s_barrier();

  #pragma unroll 1
  for (int t = 0; t < 4; ++t) {
    int tA = 2 * t + 1;
    int tB = 2 * t + 2; if (tB > 7) tB = 7;
    int tC = 2 * t + 3; if (tC > 7) tC = 7;
    LDA(0, 0); LDB(0, 0); LDB(0, 1); STAGEA(1, 1, tA); STAGEB(1, 1, tA);
      BARLG(); MMA(0, 0); MMA(0, 1); ENDPH();
    LDA(0, 1);                       STAGEA(0, 0, tB); STAGEB(0, 0, tB);
      BARLG(); MMA(1, 0); MMA(1, 1); CKPT(); ENDPH();
    LDA(1, 0); LDB(1, 0); LDB(1, 1); STAGEA(0, 1, tB); STAGEB(0, 1, tB);
      BARLG(); MMA(0, 0); MMA(0, 1); ENDPH();
    LDA(1, 1);                       STAGEA(1, 0, tC); STAGEB(1, 0, tC);
      BARLG(); MMA(1, 0); MMA(1, 1); CKPT(); ENDPH();
  }

  // epilogue: per-wave 64-col exp-sums -> LDS reduce over wc -> one store per row
  __syncthreads();
  float b2v[4];
  #pragma unroll
  for (int nf = 0; nf < 4; ++nf)
    b2v[nf] = bias[n0 + (nf >> 1) * 128 + wc * 32 + (nf & 1) * 16 + (l & 15)];
  float* eL = (float*)As;   // [4 wc][256 rows]
  #pragma unroll
  for (int mf = 0; mf < 8; ++mf) {
    #pragma unroll
    for (int r2 = 0; r2 < 4; ++r2) {
      float s = 0.f;
      #pragma unroll
      for (int nf = 0; nf < 4; ++nf)
        s += __expf(acc[mf][nf][r2] + b2v[nf]);
      s += __shfl_xor(s, 1); s += __shfl_xor(s, 2);
      s += __shfl_xor(s, 4); s += __shfl_xor(s, 8);
      if ((l & 15) == 0)
        eL[wc * 256 + (mf >> 2) * 128 + wr * 64 + (mf & 3) * 16 + (l >> 4) * 4 + r2] = s;
    }
  }
  __syncthreads();
  if (tid < 256) {
    float v = eL[tid] + eL[256 + tid] + eL[512 + tid] + eL[768 + tid];
    psum[(size_t)nt * MPAD + m0 + tid] = v;
  }
}

// ---- fused act (+toklogit) & tnet-with-reuse kernel ----
__global__ __launch_bounds__(256) void k_actnet(
    const float* __restrict__ Uw, const float* __restrict__ Vw,
    const float* __restrict__ wb1, u8* __restrict__ act8,
    const u8* __restrict__ w2t8, const int* __restrict__ sent,
    const float* __restrict__ wb2, float* __restrict__ tok_logit,
    const float* __restrict__ Ut, const float* __restrict__ Vt,
    const float* __restrict__ tb1, const float* __restrict__ tW2,
    const float* __restrict__ tb2,
    float* __restrict__ sh_lp, float* __restrict__ re_lp)
{
  __shared__ float ldsf[8192];   // act: pd[512]; tnet: Us[8][512] + Vs[8][512]
  if (blockIdx.x < 2048) {
    float* pd = ldsf;
    int p = blockIdx.x;
    int iu = 0, ju = 0;
    bool real = (p < NPTOT);
    if (p < NPAIR) {
      int i = 0, base = 0;
      while (base + (62 - i) <= p) { base += 62 - i; ++i; }
      iu = i; ju = i + 1 + (p - base);
    }                                   // p==1953 -> (0,0)
    const int srow = (p < NPAIR) ? (ju + 1) : 1;
    for (int t = threadIdx.x; t < 512; t += 256) {   // 8 rows x 64 chunks
      int b = t >> 6, c = t & 63;
      int wpos = (c >> 3) * 64 + ksl(c & 7) * 8;     // ksl-permuted 8B slot
      u64 bytes = 0;
      float s = 0.f;
      if (real) {
        const float4* u4 = (const float4*)(Uw + (size_t)(iu * BB + b) * HH);
        const float4* v4 = (const float4*)(Vw + (size_t)(ju * BB + b) * HH);
        const float4* bb4 = (const float4*)wb1;
        int dw[2] = {0, 0};
        #pragma unroll
        for (int q = 0; q < 2; ++q) {
          float4 uu = u4[c * 2 + q], vv = v4[c * 2 + q], bb = bb4[c * 2 + q];
          float v0 = fmaxf(uu.x + vv.x + bb.x, 0.f);
          float v1 = fmaxf(uu.y + vv.y + bb.y, 0.f);
          float v2 = fmaxf(uu.z + vv.z + bb.z, 0.f);
          float v3 = fmaxf(uu.w + vv.w + bb.w, 0.f);
          dw[q] = __builtin_amdgcn_cvt_pk_fp8_f32(v0, v1, dw[q], false);
          dw[q] = __builtin_amdgcn_cvt_pk_fp8_f32(v2, v3, dw[q], true);
        }
        bytes = (u64)(u32)dw[0] | ((u64)(u32)dw[1] << 32);
        int tok = sent[srow * BB + b];
        u64 wv = *(const u64*)(w2t8 + (size_t)tok * 512 + wpos);  // same permuted slot
        int aw[2] = {(int)(u32)bytes, (int)(u32)(bytes >> 32)};
        int ww[2] = {(int)(u32)wv, (int)(u32)(wv >> 32)};
        #pragma unroll
        for (int q = 0; q < 2; ++q) {
          f32x2 alo = __builtin_amdgcn_cvt_pk_f32_fp8(aw[q], false);
          f32x2 ahi = __builtin_amdgcn_cvt_pk_f32_fp8(aw[q], true);
          f32x2 wlo = __builtin_amdgcn_cvt_pk_f32_fp8(ww[q], false);
          f32x2 whi = __builtin_amdgcn_cvt_pk_f32_fp8(ww[q], true);
          s += alo[0] * wlo[0] + alo[1] * wlo[1] + ahi[0] * whi[0] + ahi[1] * whi[1];
        }
      }
      *(u64*)(act8 + (size_t)(p * 8 + b) * 512 + wpos) = bytes;
      pd[t] = s;
    }
    __syncthreads();
    if (real) {
      int wv_ = threadIdx.x >> 6, ln = threadIdx.x & 63;
      #pragma unroll
      for (int rr = 0; rr < 2; ++rr) {
        int b = wv_ * 2 + rr;
        float s = pd[b * 64 + ln];
        #pragma unroll
        for (int off = 1; off < 64; off <<= 1) s += __shfl_xor(s, off);
        if (ln == 0) {
          int tok = sent[srow * BB + b];
          tok_logit[p * 8 + b] = s + wb2[tok];
        }
      }
    }
    return;
  }
  // ----- tnet branch: block = (b, group-pair ig<=jg); 8+8 rows cached in LDS -----
  int t = blockIdx.x - 2048;          // 0..287
  int b = t & 7, pr = t >> 3;         // pr 0..35
  int ig = 0, base = 0;
  while (base + (8 - ig) <= pr) { base += 8 - ig; ++ig; }
  int jg = ig + (pr - base);
  float* Us = ldsf;                   // [8][512]
  float* Vs = ldsf + 4096;            // [8][512]
  for (int q = threadIdx.x; q < 1024; q += 256) {
    int ii = q >> 7, cc = q & 127;
    ((float4*)Us)[ii * 128 + cc] = ((const float4*)(Ut + (size_t)((ig * 8 + ii) * BB + b) * HH))[cc];
    ((float4*)Vs)[ii * 128 + cc] = ((const float4*)(Vt + (size_t)((jg * 8 + ii) * BB + b) * HH))[cc];
  }
  __syncthreads();
  int lane = threadIdx.x & 63, wv_ = threadIdx.x >> 6;
  float b1r[8], w2r[8];
  #pragma unroll
  for (int k = 0; k < 8; ++k) { b1r[k] = tb1[lane + 64 * k]; w2r[k] = tW2[lane + 64 * k]; }
  for (int pp = wv_; pp < 64; pp += 4) {
    int ii = pp >> 3, jj = pp & 7;
    int i = ig * 8 + ii, j = jg * 8 + jj;
    float s = 0.f;
    #pragma unroll
    for (int k = 0; k < 8; ++k)
      s += fmaxf(Us[ii * 512 + lane + 64 * k] + Vs[jj * 512 + lane + 64 * k] + b1r[k], 0.f) * w2r[k];
    #pragma unroll
    for (int off = 1; off < 64; off <<= 1) s += __shfl_xor(s, off);
    if (lane == 0 && i < j) {
      float tv = s + tb2[0];
      re_lp[(i * 64 + j) * 8 + b] = logsig(tv);
      sh_lp[(i * 64 + j) * 8 + b] = logsig(-tv);
    }
  }
}

// inside DP: conflict-free tw/trT formulation; psum 32-slot reduce inlined.
__global__ __launch_bounds__(1024) void k_dp(const float* __restrict__ sh_lp, const float* __restrict__ re_lp,
                                             const float* __restrict__ tok_logit, const float* __restrict__ psum,
                                             float* __restrict__ finals) {
  int b = blockIdx.x;
  __shared__ float tw[4096];
  __shared__ float trT[4096];
  __shared__ float wplL[4096];
  __shared__ float relL[4096];
  int tid = threadIdx.x;
  for (int idx = tid; idx < 4096; idx += 1024) {
    int i = idx >> 6, j = idx & 63;
    float w = NEG;
    if (i < j && j <= 62) {
      int p = i * 62 - i * (i - 1) / 2 + (j - i - 1);
      int r = p * 8 + b;
      float se = 0.f;
      #pragma unroll 8
      for (int sl2 = 0; sl2 < 32; ++sl2) se += psum[(size_t)sl2 * MPAD + r];
      w = sh_lp[idx * 8 + b] + (tok_logit[r] - __logf(se));
    }
    wplL[idx] = w;
    relL[idx] = (i < j) ? re_lp[idx * 8 + b] : NEG;
  }
  __syncthreads();
  for (int idx = tid; idx < 4096; idx += 1024) {
    tw[idx] = NEG + wplL[idx];
    trT[idx] = NEG + relL[(idx & 63) * 64 + (idx >> 6)];
  }
  __syncthreads();
  if (tid == 0) {
    int r0i = NPAIR * 8 + b;
    float se = 0.f;
    #pragma unroll 8
    for (int sl2 = 0; sl2 < 32; ++sl2) se += psum[(size_t)sl2 * MPAD + r0i];
    float v0 = tok_logit[r0i] - __logf(se);
    tw[1] = v0 + wplL[1];
    trT[1 * 64 + 0] = v0 + relL[0 * 64 + 1];
  }
  if (tid >= 1 && tid <= 62) {
    tw[tid * 64 + tid + 1] = wplL[tid * 64 + tid + 1];
    trT[(tid + 1) * 64 + tid] = relL[tid * 64 + tid + 1];
  }
  __syncthreads();
  int lane = tid & 63, wave = tid >> 6;   // 16 waves
  for (int g = 2; g <= 63; ++g) {
    int cnt = 64 - g;                     // i in [0, 63-g]
    if (g <= 17) {
      int seg = lane >> 4, sl = lane & 15;
      int i = wave * 4 + seg;
      if (i < cnt) {
        int m = sl + 1;
        int j = i + g, k = i + m;
        float sc = (m < g) ? tw[i * 64 + k] + trT[j * 64 + k] : NEG;
        float mx = sc;
        #pragma unroll
        for (int off = 1; off < 16; off <<= 1) mx = fmaxf(mx, __shfl_xor(mx, off));
        float e = (m < g) ? __expf(sc - mx) : 0.f;
        #pragma unroll
        for (int off = 1; off < 16; off <<= 1) e += __shfl_xor(e, off);
        if (sl == 0) {
          float val = __logf(e) + mx;
          tw[i * 64 + j] = val + wplL[i * 64 + j];
          trT[j * 64 + i] = val + relL[i * 64 + j];
        }
      }
    } else {
      for (int i = wave; i < cnt; i += 16) {
        int m = lane + 1;
        int j = i + g, k = i + m;
        float sc = (m < g) ? tw[i * 64 + k] + trT[j * 64 + k] : NEG;
        float mx = sc;
        #pragma unroll
        for (int off = 1; off < 64; off <<= 1) mx = fmaxf(mx, __shfl_xor(mx, off));
        float e = (m < g) ? __expf(sc - mx) : 0.f;
        #pragma unroll
        for (int off = 1; off < 64; off <<= 1) e += __shfl_xor(e, off);
        if (lane == 0) {
          float val = __logf(e) + mx;
          tw[i * 64 + j] = val + wplL[i * 64 + j];
          trT[j * 64 + i] = val + relL[i * 64 + j];
        }
      }
    }
    __syncthreads();
  }
  if (tid == 0) finals[b] = trT[63 * 64 + 0];
}

__global__ void k_final(const float* __restrict__ finals, float* __restrict__ out) {
  if (threadIdx.x == 0) {
    float s = 0.f;
    for (int b = 0; b < 8; ++b) s += finals[b];
    out[0] = -s;
  }
}

extern "C" void kernel_launch(void* const* d_in, const int* in_sizes, int n_in,
                              void* d_out, int out_size, void* d_ws, size_t ws_size,
                              hipStream_t stream) {
  const float* h    = (const float*)d_in[0];
  const int*   sent = (const int*)d_in[1];
  const float* tW1  = (const float*)d_in[2];
  const float* tb1  = (const float*)d_in[3];
  const float* tW2  = (const float*)d_in[4];
  const float* tb2  = (const float*)d_in[5];
  const float* wW1  = (const float*)d_in[6];
  const float* wb1  = (const float*)d_in[7];
  const float* wW2  = (const float*)d_in[8];
  const float* wb2  = (const float*)d_in[9];
  float* out = (float*)d_out;

  char* ws = (char*)d_ws;
  size_t off = 0;
  auto alloc = [&](size_t bytes) { char* p = ws + off; off += (bytes + 255) & ~(size_t)255; return p; };
  bf16_t* hbf    = (bf16_t*)alloc((size_t)512 * 512 * 2);
  bf16_t* tW1T   = (bf16_t*)alloc((size_t)512 * 1024 * 2);
  bf16_t* wW1T   = (bf16_t*)alloc((size_t)512 * 1024 * 2);
  u8*     w2t8   = (u8*)alloc((size_t)VV * HH);
  float*  Ut     = (float*)alloc((size_t)512 * 512 * 4);
  float*  Vt     = (float*)alloc((size_t)512 * 512 * 4);
  float*  Uw     = (float*)alloc((size_t)512 * 512 * 4);
  float*  Vw     = (float*)alloc((size_t)512 * 512 * 4);
  u8*     act8   = (u8*)alloc((size_t)MPAD * HH);
  float*  psum   = (float*)alloc((size_t)32 * MPAD * 4);
  float*  tokl   = (float*)alloc((size_t)MPAD * 4);
  float*  shlp   = (float*)alloc((size_t)32768 * 4);
  float*  relp   = (float*)alloc((size_t)32768 * 4);
  float*  finals = (float*)alloc(256);

  k_prep<<<1280, 256, 0, stream>>>(h, hbf, tW1, tW1T, wW1, wW1T);
  k_gemm4t<<<4160, 256, 0, stream>>>(hbf, tW1T, wW1T, Ut, Vt, Uw, Vw, wW2, w2t8);
  k_actnet<<<2048 + 288, 256, 0, stream>>>(Uw, Vw, wb1, act8, w2t8, sent, wb2, tokl,
                                           Ut, Vt, tb1, tW2, tb2, shlp, relp);
  k_gemm256<<<2048, 512, 0, stream>>>(act8, w2t8, wb2, psum);
  k_dp<<<8, 1024, 0, stream>>>(shlp, relp, tokl, psum, finals);
  k_final<<<1, 64, 0, stream>>>(finals, out);
}

// Round 15
// 267.954 us; speedup vs baseline: 1.0912x; 1.0912x over previous
//
#include <hip/hip_runtime.h>
#include <hip/hip_bf16.h>
#include <hip/hip_fp8.h>
#include <math.h>

#define NEG (-1.0e9f)

typedef __bf16 bf16_t;
typedef __bf16 bf16x4 __attribute__((ext_vector_type(4)));
typedef __bf16 bf16x8 __attribute__((ext_vector_type(8)));
typedef float f32x2 __attribute__((ext_vector_type(2)));
typedef float f32x4 __attribute__((ext_vector_type(4)));
typedef long i64x2 __attribute__((ext_vector_type(2)));
typedef unsigned char u8;
typedef unsigned int u32;
typedef unsigned long long u64;

#define SS 64
#define BB 8
#define HH 512
#define VV 8192
#define NPAIR 1953          /* upper-tri pairs (i<j) over [0,63) */
#define NPTOT 1954          /* + (0,0) row for init_lp */
#define MROWS (NPTOT*BB)    /* 15632 */
#define MPAD  15872         /* 62*256 */

__device__ __forceinline__ float logsig(float x) {
  return fminf(x, 0.f) - __logf(1.f + __expf(-fabsf(x)));
}
__device__ __forceinline__ u8 f2q(float x) { __hip_fp8_e4m3 q(x); return q.__x; }
// k-order permutation within each 64B group: chunk c -> slot 2*(c&3)+(c>>2)
__device__ __forceinline__ int ksl(int c) { return 2 * (c & 3) + (c >> 2); }

// ---------------- preprocessing: h cvt + 2 bf16 transposes ----------------
__global__ __launch_bounds__(256) void k_prep(
    const float* __restrict__ h,   bf16_t* __restrict__ hbf,
    const float* __restrict__ tW1, bf16_t* __restrict__ tW1T,
    const float* __restrict__ wW1, bf16_t* __restrict__ wW1T) {
  __shared__ float tile[32][33];
  int blk = blockIdx.x, tid = threadIdx.x;
  if (blk < 256) {                      // h: 262144 floats, float4-vectorized
    int gi = blk * 256 + tid;
    float4 v = ((const float4*)h)[gi];
    bf16x4 o = {(bf16_t)v.x, (bf16_t)v.y, (bf16_t)v.z, (bf16_t)v.w};
    ((bf16x4*)hbf)[gi] = o;
    return;
  }
  const float* in; bf16_t* out; int R = 1024, C = 512, t;
  if (blk < 768) { in = tW1; out = tW1T; t = blk - 256; }
  else           { in = wW1; out = wW1T; t = blk - 768; }
  int xt = C / 32;
  int c0 = (t % xt) * 32, r0 = (t / xt) * 32;
  int tx = tid & 31, ty = tid >> 5;
  for (int i = ty; i < 32; i += 8)
    tile[i][tx] = in[(size_t)(r0 + i) * C + c0 + tx];
  __syncthreads();
  for (int i = ty; i < 32; i += 8)
    out[(size_t)(c0 + i) * R + r0 + tx] = (bf16_t)tile[tx][i];
}

// ------- fused: 4x small GEMM (blocks 0..63) + wW2->fp8 ksl transpose (blocks 64..4159) ---
__global__ __launch_bounds__(256) void k_gemm4t(
    const bf16_t* __restrict__ A,
    const bf16_t* __restrict__ tW1T, const bf16_t* __restrict__ wW1T,
    float* __restrict__ Ut, float* __restrict__ Vt,
    float* __restrict__ Uw, float* __restrict__ Vw,
    const float* __restrict__ wW2, u8* __restrict__ w2t8)
{
  __shared__ __align__(16) char lds_raw[16384];
  const int tid = threadIdx.x;
  if (blockIdx.x >= 64) {
    float* tile = (float*)lds_raw;      // [32][33]
    int t = blockIdx.x - 64;            // 0..4095
    int c0 = (t % 256) * 32, r0 = (t / 256) * 32;
    int tx = tid & 31, ty = tid >> 5;
    for (int i = ty; i < 32; i += 8)
      tile[i * 33 + tx] = wW2[(size_t)(r0 + i) * 8192 + c0 + tx];
    __syncthreads();
    for (int i = ty; i < 32; i += 8) {
      int k = r0 + tx;
      int pos = (k >> 6) * 64 + ksl((k >> 3) & 7) * 8 + (k & 7);
      w2t8[(size_t)(c0 + i) * 512 + pos] = f2q(tile[tx * 33 + i]);
    }
    return;
  }
  bf16_t* As = (bf16_t*)lds_raw;
  bf16_t* Bs = (bf16_t*)(lds_raw + 8192);
  const int lane = tid & 63;
  const int wave = tid >> 6;
  const int wr = wave >> 1, wc = wave & 1;
  const int sel = blockIdx.x >> 4, sub = blockIdx.x & 15;
  const bf16_t* BT = (sel < 2 ? tW1T : wW1T) + (sel & 1) * 512;
  float* Cout = (sel == 0) ? Ut : (sel == 1) ? Vt : (sel == 2) ? Uw : Vw;
  const int m0 = (sub & 3) * 128, n0 = (sub >> 2) * 128;
  const int lda = 512, ldb = 1024, ldc = 512;

  const int rowS = tid >> 2;
  const int kS = (tid & 3) * 8;
  const bf16_t* gA0 = A + (size_t)(m0 + rowS) * lda + kS;
  const bf16_t* gA1 = A + (size_t)(m0 + rowS + 64) * lda + kS;
  const bf16_t* gB0 = BT + (size_t)(n0 + rowS) * ldb + kS;
  const bf16_t* gB1 = BT + (size_t)(n0 + rowS + 64) * ldb + kS;

  f32x4 acc[4][4] = {};
  const int aoff = (wr * 64 + (lane & 15)) * 32 + (lane >> 4) * 8;
  const int boff = (wc * 64 + (lane & 15)) * 32 + (lane >> 4) * 8;

  for (int k0 = 0; k0 < 512; k0 += 32) {
    __builtin_amdgcn_global_load_lds((const __attribute__((address_space(1))) void*)(gA0 + k0),
        (__attribute__((address_space(3))) void*)(As + wave * 512), 16, 0, 0);
    __builtin_amdgcn_global_load_lds((const __attribute__((address_space(1))) void*)(gA1 + k0),
        (__attribute__((address_space(3))) void*)(As + 2048 + wave * 512), 16, 0, 0);
    __builtin_amdgcn_global_load_lds((const __attribute__((address_space(1))) void*)(gB0 + k0),
        (__attribute__((address_space(3))) void*)(Bs + wave * 512), 16, 0, 0);
    __builtin_amdgcn_global_load_lds((const __attribute__((address_space(1))) void*)(gB1 + k0),
        (__attribute__((address_space(3))) void*)(Bs + 2048 + wave * 512), 16, 0, 0);
    __syncthreads();
    bf16x8 af[4], bfr[4];
    #pragma unroll
    for (int mf = 0; mf < 4; ++mf) af[mf] = *(const bf16x8*)&As[aoff + mf * 16 * 32];
    #pragma unroll
    for (int nf = 0; nf < 4; ++nf) bfr[nf] = *(const bf16x8*)&Bs[boff + nf * 16 * 32];
    #pragma unroll
    for (int mf = 0; mf < 4; ++mf)
      #pragma unroll
      for (int nf = 0; nf < 4; ++nf)
        acc[mf][nf] = __builtin_amdgcn_mfma_f32_16x16x32_bf16(af[mf], bfr[nf], acc[mf][nf], 0, 0, 0);
    __syncthreads();
  }
  #pragma unroll
  for (int mf = 0; mf < 4; ++mf)
    #pragma unroll
    for (int r2 = 0; r2 < 4; ++r2) {
      int grow = m0 + wr * 64 + mf * 16 + (lane >> 4) * 4 + r2;
      #pragma unroll
      for (int nf = 0; nf < 4; ++nf) {
        int gcol = n0 + wc * 64 + nf * 16 + (lane & 15);
        Cout[(size_t)grow * ldc + gcol] = acc[mf][nf][r2];
      }
    }
}

// ---------------- fp8 256x256-tile GEMM, 4-phase/iter (r12-measured loop) ----------------
// grid 1984 = 62 m-tiles x 32 n-tiles; wg = xcd*248 + sub (bijective, 1984%8==0);
// mt = wg>>5 (consecutive wg share A-band per XCD), nt = wg&31.
// epilogue: LDS-reduce 4 wc-wave partials -> one plain store per row into psum[nt][row]
#define STAGEA(b, h, kt) do { \
  const u8* _s = A8 + (size_t)(m0 + (h)*128 + (tid>>2)) * 512 + (kt)*64 + csrc; \
  __builtin_amdgcn_global_load_lds((const __attribute__((address_space(1))) void*)_s, \
    (__attribute__((address_space(3))) void*)(As + (b)*16384 + (h)*8192 + (tid>>6)*1024), 16, 0, 0); \
} while(0)

#define STAGEB(b, h, kt) do { \
  const u8* _s = BT8 + (size_t)(n0 + (h)*128 + (tid>>2)) * 512 + (kt)*64 + csrc; \
  __builtin_amdgcn_global_load_lds((const __attribute__((address_space(1))) void*)_s, \
    (__attribute__((address_space(3))) void*)(Bs + (b)*16384 + (h)*8192 + (tid>>6)*1024), 16, 0, 0); \
} while(0)

#define LDA(b, mh) do { \
  _Pragma("unroll") \
  for (int _m = 0; _m < 4; ++_m) \
    afv[_m] = *(const i64x2*)(As + (b)*16384 + (mh)*8192 + ardE + _m*1024); \
} while(0)

#define LDB(b, nh) do { \
  _Pragma("unroll") \
  for (int _n = 0; _n < 2; ++_n) \
    bfv[nh][_n] = *(const i64x2*)(Bs + (b)*16384 + (nh)*8192 + brdE + _n*1024); \
} while(0)

#define MMA(mh, nh) do { \
  __builtin_amdgcn_s_setprio(1); \
  _Pragma("unroll") \
  for (int _m = 0; _m < 4; ++_m) \
    _Pragma("unroll") \
    for (int _n = 0; _n < 2; ++_n) { \
      acc[(mh)*4+_m][(nh)*2+_n] = __builtin_amdgcn_mfma_f32_16x16x32_fp8_fp8( \
          afv[_m][0], bfv[nh][_n][0], acc[(mh)*4+_m][(nh)*2+_n], 0, 0, 0); \
      acc[(mh)*4+_m][(nh)*2+_n] = __builtin_amdgcn_mfma_f32_16x16x32_fp8_fp8( \
          afv[_m][1], bfv[nh][_n][1], acc[(mh)*4+_m][(nh)*2+_n], 0, 0, 0); \
    } \
  __builtin_amdgcn_s_setprio(0); \
} while(0)

#define BARLG() do { __builtin_amdgcn_s_barrier(); \
  asm volatile("s_waitcnt lgkmcnt(0)" ::: "memory"); \
  __builtin_amdgcn_sched_barrier(0); } while(0)
#define ENDPH() __builtin_amdgcn_s_barrier()
#define CKPT() asm volatile("s_waitcnt vmcnt(2)" ::: "memory")

__global__ __launch_bounds__(512, 2) void k_gemm256(
    const u8* __restrict__ A8,
    const u8* __restrict__ BT8,
    const float* __restrict__ bias,
    float* __restrict__ psum)
{
  __shared__ __align__(16) u8 As[2 * 16384];   // [buf][half][128 rows][64B]
  __shared__ __align__(16) u8 Bs[2 * 16384];
  const int tid = threadIdx.x;
  const int l = tid & 63;
  const int wave = tid >> 6;
  const int wr = wave >> 2, wc = wave & 3;   // 2M x 4N waves

  const int xcd = blockIdx.x & 7, sub = blockIdx.x >> 3;   // sub 0..247
  const int wg = xcd * 248 + sub;
  const int mt = wg >> 5;                    // 0..61
  const int nt = wg & 31;
  const int m0 = mt * 256, n0 = nt * 256;

  const int csrc = (((tid & 3) ^ ((tid >> 3) & 3)) << 4);
  const int rsw = (((l >> 4) ^ ((l & 15) >> 1)) & 3) << 4;
  const int ardE = (wr * 64 + (l & 15)) * 64 + rsw;
  const int brdE = (wc * 32 + (l & 15)) * 64 + rsw;

  f32x4 acc[8][4] = {};
  i64x2 afv[4];
  i64x2 bfv[2][2];

  // prologue: K-tile 0 -> buf0 full (4 issues); K-tile 1 -> buf1.A0,B0 (2 issues)
  STAGEA(0, 0, 0); STAGEA(0, 1, 0); STAGEB(0, 0, 0); STAGEB(0, 1, 0);
  STAGEA(1, 0, 1); STAGEB(1, 0, 1);
  CKPT();
  __builtin_amdgcn_s_barrier();

  #pragma unroll 1
  for (int t = 0; t < 4; ++t) {
    int tA = 2 * t + 1;
    int tB = 2 * t + 2; if (tB > 7) tB = 7;
    int tC = 2 * t + 3; if (tC > 7) tC = 7;
    LDA(0, 0); LDB(0, 0); LDB(0, 1); STAGEA(1, 1, tA); STAGEB(1, 1, tA);
      BARLG(); MMA(0, 0); MMA(0, 1); ENDPH();
    LDA(0, 1);                       STAGEA(0, 0, tB); STAGEB(0, 0, tB);
      BARLG(); MMA(1, 0); MMA(1, 1); CKPT(); ENDPH();
    LDA(1, 0); LDB(1, 0); LDB(1, 1); STAGEA(0, 1, tB); STAGEB(0, 1, tB);
      BARLG(); MMA(0, 0); MMA(0, 1); ENDPH();
    LDA(1, 1);                       STAGEA(1, 0, tC); STAGEB(1, 0, tC);
      BARLG(); MMA(1, 0); MMA(1, 1); CKPT(); ENDPH();
  }

  // epilogue: per-wave 64-col exp-sums -> LDS reduce over wc -> one store per row
  __syncthreads();
  float b2v[4];
  #pragma unroll
  for (int nf = 0; nf < 4; ++nf)
    b2v[nf] = bias[n0 + (nf >> 1) * 128 + wc * 32 + (nf & 1) * 16 + (l & 15)];
  float* eL = (float*)As;   // [4 wc][256 rows]
  #pragma unroll
  for (int mf = 0; mf < 8; ++mf) {
    #pragma unroll
    for (int r2 = 0; r2 < 4; ++r2) {
      float s = 0.f;
      #pragma unroll
      for (int nf = 0; nf < 4; ++nf)
        s += __expf(acc[mf][nf][r2] + b2v[nf]);
      s += __shfl_xor(s, 1); s += __shfl_xor(s, 2);
      s += __shfl_xor(s, 4); s += __shfl_xor(s, 8);
      if ((l & 15) == 0)
        eL[wc * 256 + (mf >> 2) * 128 + wr * 64 + (mf & 3) * 16 + (l >> 4) * 4 + r2] = s;
    }
  }
  __syncthreads();
  if (tid < 256) {
    float v = eL[tid] + eL[256 + tid] + eL[512 + tid] + eL[768 + tid];
    psum[(size_t)nt * MPAD + m0 + tid] = v;
  }
}

// sumexp[row] = sum over 32 psum slots (coalesced)
__global__ __launch_bounds__(256) void k_red(const float* __restrict__ psum, float* __restrict__ sumexp) {
  int r = blockIdx.x * 256 + threadIdx.x;
  float s = 0.f;
  #pragma unroll 8
  for (int sl = 0; sl < 32; ++sl) s += psum[(size_t)sl * MPAD + r];
  sumexp[r] = s;
}

// ---- fused act (+toklogit) & tnet-with-reuse kernel ----
__global__ __launch_bounds__(256) void k_actnet(
    const float* __restrict__ Uw, const float* __restrict__ Vw,
    const float* __restrict__ wb1, u8* __restrict__ act8,
    const u8* __restrict__ w2t8, const int* __restrict__ sent,
    const float* __restrict__ wb2, float* __restrict__ tok_logit,
    const float* __restrict__ Ut, const float* __restrict__ Vt,
    const float* __restrict__ tb1, const float* __restrict__ tW2,
    const float* __restrict__ tb2,
    float* __restrict__ sh_lp, float* __restrict__ re_lp)
{
  __shared__ float ldsf[8192];   // act: pd[512]; tnet: Us[8][512] + Vs[8][512]
  if (blockIdx.x < 1984) {
    float* pd = ldsf;
    int p = blockIdx.x;
    int iu = 0, ju = 0;
    bool real = (p < NPTOT);
    if (p < NPAIR) {
      int i = 0, base = 0;
      while (base + (62 - i) <= p) { base += 62 - i; ++i; }
      iu = i; ju = i + 1 + (p - base);
    }                                   // p==1953 -> (0,0)
    const int srow = (p < NPAIR) ? (ju + 1) : 1;
    for (int t = threadIdx.x; t < 512; t += 256) {   // 8 rows x 64 chunks
      int b = t >> 6, c = t & 63;
      int wpos = (c >> 3) * 64 + ksl(c & 7) * 8;     // ksl-permuted 8B slot
      u64 bytes = 0;
      float s = 0.f;
      if (real) {
        const float4* u4 = (const float4*)(Uw + (size_t)(iu * BB + b) * HH);
        const float4* v4 = (const float4*)(Vw + (size_t)(ju * BB + b) * HH);
        const float4* bb4 = (const float4*)wb1;
        int dw[2] = {0, 0};
        #pragma unroll
        for (int q = 0; q < 2; ++q) {
          float4 uu = u4[c * 2 + q], vv = v4[c * 2 + q], bb = bb4[c * 2 + q];
          float v0 = fmaxf(uu.x + vv.x + bb.x, 0.f);
          float v1 = fmaxf(uu.y + vv.y + bb.y, 0.f);
          float v2 = fmaxf(uu.z + vv.z + bb.z, 0.f);
          float v3 = fmaxf(uu.w + vv.w + bb.w, 0.f);
          dw[q] = __builtin_amdgcn_cvt_pk_fp8_f32(v0, v1, dw[q], false);
          dw[q] = __builtin_amdgcn_cvt_pk_fp8_f32(v2, v3, dw[q], true);
        }
        bytes = (u64)(u32)dw[0] | ((u64)(u32)dw[1] << 32);
        int tok = sent[srow * BB + b];
        u64 wv = *(const u64*)(w2t8 + (size_t)tok * 512 + wpos);  // same permuted slot
        int aw[2] = {(int)(u32)bytes, (int)(u32)(bytes >> 32)};
        int ww[2] = {(int)(u32)wv, (int)(u32)(wv >> 32)};
        #pragma unroll
        for (int q = 0; q < 2; ++q) {
          f32x2 alo = __builtin_amdgcn_cvt_pk_f32_fp8(aw[q], false);
          f32x2 ahi = __builtin_amdgcn_cvt_pk_f32_fp8(aw[q], true);
          f32x2 wlo = __builtin_amdgcn_cvt_pk_f32_fp8(ww[q], false);
          f32x2 whi = __builtin_amdgcn_cvt_pk_f32_fp8(ww[q], true);
          s += alo[0] * wlo[0] + alo[1] * wlo[1] + ahi[0] * whi[0] + ahi[1] * whi[1];
        }
      }
      *(u64*)(act8 + (size_t)(p * 8 + b) * 512 + wpos) = bytes;
      pd[t] = s;
    }
    __syncthreads();
    if (real) {
      int wv_ = threadIdx.x >> 6, ln = threadIdx.x & 63;
      #pragma unroll
      for (int rr = 0; rr < 2; ++rr) {
        int b = wv_ * 2 + rr;
        float s = pd[b * 64 + ln];
        #pragma unroll
        for (int off = 1; off < 64; off <<= 1) s += __shfl_xor(s, off);
        if (ln == 0) {
          int tok = sent[srow * BB + b];
          tok_logit[p * 8 + b] = s + wb2[tok];
        }
      }
    }
    return;
  }
  // ----- tnet branch: block = (b, group-pair ig<=jg); 8+8 rows cached in LDS -----
  int t = blockIdx.x - 1984;          // 0..287
  int b = t & 7, pr = t >> 3;         // pr 0..35
  int ig = 0, base = 0;
  while (base + (8 - ig) <= pr) { base += 8 - ig; ++ig; }
  int jg = ig + (pr - base);
  float* Us = ldsf;                   // [8][512]
  float* Vs = ldsf + 4096;            // [8][512]
  for (int q = threadIdx.x; q < 1024; q += 256) {
    int ii = q >> 7, cc = q & 127;
    ((float4*)Us)[ii * 128 + cc] = ((const float4*)(Ut + (size_t)((ig * 8 + ii) * BB + b) * HH))[cc];
    ((float4*)Vs)[ii * 128 + cc] = ((const float4*)(Vt + (size_t)((jg * 8 + ii) * BB + b) * HH))[cc];
  }
  __syncthreads();
  int lane = threadIdx.x & 63, wv_ = threadIdx.x >> 6;
  float b1r[8], w2r[8];
  #pragma unroll
  for (int k = 0; k < 8; ++k) { b1r[k] = tb1[lane + 64 * k]; w2r[k] = tW2[lane + 64 * k]; }
  for (int pp = wv_; pp < 64; pp += 4) {
    int ii = pp >> 3, jj = pp & 7;
    int i = ig * 8 + ii, j = jg * 8 + jj;
    float s = 0.f;
    #pragma unroll
    for (int k = 0; k < 8; ++k)
      s += fmaxf(Us[ii * 512 + lane + 64 * k] + Vs[jj * 512 + lane + 64 * k] + b1r[k], 0.f) * w2r[k];
    #pragma unroll
    for (int off = 1; off < 64; off <<= 1) s += __shfl_xor(s, off);
    if (lane == 0 && i < j) {
      float tv = s + tb2[0];
      re_lp[(i * 64 + j) * 8 + b] = logsig(tv);
      sh_lp[(i * 64 + j) * 8 + b] = logsig(-tv);
    }
  }
}

// inside DP: conflict-free tw/trT formulation (r13-measured).
__global__ __launch_bounds__(1024) void k_dp(const float* __restrict__ sh_lp, const float* __restrict__ re_lp,
                                             const float* __restrict__ tok_logit, const float* __restrict__ sumexp,
                                             float* __restrict__ finals) {
  int b = blockIdx.x;
  __shared__ float tw[4096];
  __shared__ float trT[4096];
  __shared__ float wplL[4096];
  __shared__ float relL[4096];
  int tid = threadIdx.x;
  for (int idx = tid; idx < 4096; idx += 1024) {
    int i = idx >> 6, j = idx & 63;
    float w = NEG;
    if (i < j && j <= 62) {
      int p = i * 62 - i * (i - 1) / 2 + (j - i - 1);
      int r = p * 8 + b;
      w = sh_lp[idx * 8 + b] + (tok_logit[r] - __logf(sumexp[r]));
    }
    wplL[idx] = w;
    relL[idx] = (i < j) ? re_lp[idx * 8 + b] : NEG;
  }
  __syncthreads();
  for (int idx = tid; idx < 4096; idx += 1024) {
    tw[idx] = NEG + wplL[idx];
    trT[idx] = NEG + relL[(idx & 63) * 64 + (idx >> 6)];
  }
  __syncthreads();
  if (tid == 0) {
    float v0 = tok_logit[NPAIR * 8 + b] - __logf(sumexp[NPAIR * 8 + b]);
    tw[1] = v0 + wplL[1];
    trT[1 * 64 + 0] = v0 + relL[0 * 64 + 1];
  }
  if (tid >= 1 && tid <= 62) {
    tw[tid * 64 + tid + 1] = wplL[tid * 64 + tid + 1];
    trT[(tid + 1) * 64 + tid] = relL[tid * 64 + tid + 1];
  }
  __syncthreads();
  int lane = tid & 63, wave = tid >> 6;   // 16 waves
  for (int g = 2; g <= 63; ++g) {
    int cnt = 64 - g;                     // i in [0, 63-g]
    if (g <= 17) {
      int seg = lane >> 4, sl = lane & 15;
      int i = wave * 4 + seg;
      if (i < cnt) {
        int m = sl + 1;
        int j = i + g, k = i + m;
        float sc = (m < g) ? tw[i * 64 + k] + trT[j * 64 + k] : NEG;
        float mx = sc;
        #pragma unroll
        for (int off = 1; off < 16; off <<= 1) mx = fmaxf(mx, __shfl_xor(mx, off));
        float e = (m < g) ? __expf(sc - mx) : 0.f;
        #pragma unroll
        for (int off = 1; off < 16; off <<= 1) e += __shfl_xor(e, off);
        if (sl == 0) {
          float val = __logf(e) + mx;
          tw[i * 64 + j] = val + wplL[i * 64 + j];
          trT[j * 64 + i] = val + relL[i * 64 + j];
        }
      }
    } else {
      for (int i = wave; i < cnt; i += 16) {
        int m = lane + 1;
        int j = i + g, k = i + m;
        float sc = (m < g) ? tw[i * 64 + k] + trT[j * 64 + k] : NEG;
        float mx = sc;
        #pragma unroll
        for (int off = 1; off < 64; off <<= 1) mx = fmaxf(mx, __shfl_xor(mx, off));
        float e = (m < g) ? __expf(sc - mx) : 0.f;
        #pragma unroll
        for (int off = 1; off < 64; off <<= 1) e += __shfl_xor(e, off);
        if (lane == 0) {
          float val = __logf(e) + mx;
          tw[i * 64 + j] = val + wplL[i * 64 + j];
          trT[j * 64 + i] = val + relL[i * 64 + j];
        }
      }
    }
    __syncthreads();
  }
  if (tid == 0) finals[b] = trT[63 * 64 + 0];
}

__global__ void k_final(const float* __restrict__ finals, float* __restrict__ out) {
  if (threadIdx.x == 0) {
    float s = 0.f;
    for (int b = 0; b < 8; ++b) s += finals[b];
    out[0] = -s;
  }
}

extern "C" void kernel_launch(void* const* d_in, const int* in_sizes, int n_in,
                              void* d_out, int out_size, void* d_ws, size_t ws_size,
                              hipStream_t stream) {
  const float* h    = (const float*)d_in[0];
  const int*   sent = (const int*)d_in[1];
  const float* tW1  = (const float*)d_in[2];
  const float* tb1  = (const float*)d_in[3];
  const float* tW2  = (const float*)d_in[4];
  const float* tb2  = (const float*)d_in[5];
  const float* wW1  = (const float*)d_in[6];
  const float* wb1  = (const float*)d_in[7];
  const float* wW2  = (const float*)d_in[8];
  const float* wb2  = (const float*)d_in[9];
  float* out = (float*)d_out;

  char* ws = (char*)d_ws;
  size_t off = 0;
  auto alloc = [&](size_t bytes) { char* p = ws + off; off += (bytes + 255) & ~(size_t)255; return p; };
  bf16_t* hbf    = (bf16_t*)alloc((size_t)512 * 512 * 2);
  bf16_t* tW1T   = (bf16_t*)alloc((size_t)512 * 1024 * 2);
  bf16_t* wW1T   = (bf16_t*)alloc((size_t)512 * 1024 * 2);
  u8*     w2t8   = (u8*)alloc((size_t)VV * HH);
  float*  Ut     = (float*)alloc((size_t)512 * 512 * 4);
  float*  Vt     = (float*)alloc((size_t)512 * 512 * 4);
  float*  Uw     = (float*)alloc((size_t)512 * 512 * 4);
  float*  Vw     = (float*)alloc((size_t)512 * 512 * 4);
  u8*     act8   = (u8*)alloc((size_t)MPAD * HH);
  float*  psum   = (float*)alloc((size_t)32 * MPAD * 4);
  float*  sumexp = (float*)alloc((size_t)MPAD * 4);
  float*  tokl   = (float*)alloc((size_t)MPAD * 4);
  float*  shlp   = (float*)alloc((size_t)32768 * 4);
  float*  relp   = (float*)alloc((size_t)32768 * 4);
  float*  finals = (float*)alloc(256);

  k_prep<<<1280, 256, 0, stream>>>(h, hbf, tW1, tW1T, wW1, wW1T);
  k_gemm4t<<<4160, 256, 0, stream>>>(hbf, tW1T, wW1T, Ut, Vt, Uw, Vw, wW2, w2t8);
  k_actnet<<<1984 + 288, 256, 0, stream>>>(Uw, Vw, wb1, act8, w2t8, sent, wb2, tokl,
                                           Ut, Vt, tb1, tW2, tb2, shlp, relp);
  k_gemm256<<<1984, 512, 0, stream>>>(act8, w2t8, wb2, psum);
  k_red<<<MPAD / 256, 256, 0, stream>>>(psum, sumexp);
  k_dp<<<8, 1024, 0, stream>>>(shlp, relp, tokl, sumexp, finals);
  k_final<<<1, 64, 0, stream>>>(finals, out);
}

// Round 16
// 264.811 us; speedup vs baseline: 1.1041x; 1.0119x over previous
//
#include <hip/hip_runtime.h>
#include <hip/hip_bf16.h>
#include <hip/hip_fp8.h>
#include <math.h>

#define NEG (-1.0e9f)

typedef __bf16 bf16_t;
typedef __bf16 bf16x4 __attribute__((ext_vector_type(4)));
typedef __bf16 bf16x8 __attribute__((ext_vector_type(8)));
typedef float f32x2 __attribute__((ext_vector_type(2)));
typedef float f32x4 __attribute__((ext_vector_type(4)));
typedef long i64x2 __attribute__((ext_vector_type(2)));
typedef unsigned char u8;
typedef unsigned int u32;
typedef unsigned long long u64;

#define SS 64
#define BB 8
#define HH 512
#define VV 8192
#define NPAIR 1953          /* upper-tri pairs (i<j) over [0,63) */
#define NPTOT 1954          /* + (0,0) row for init_lp */
#define MROWS (NPTOT*BB)    /* 15632 */
#define MPAD  16384         /* 64*256 */

__device__ __forceinline__ float logsig(float x) {
  return fminf(x, 0.f) - __logf(1.f + __expf(-fabsf(x)));
}
__device__ __forceinline__ u8 f2q(float x) { __hip_fp8_e4m3 q(x); return q.__x; }
// k-order permutation within each 64B group: chunk c -> slot 2*(c&3)+(c>>2)
__device__ __forceinline__ int ksl(int c) { return 2 * (c & 3) + (c >> 2); }

// ---------------- preprocessing: h cvt + 2 bf16 transposes ----------------
__global__ __launch_bounds__(256) void k_prep(
    const float* __restrict__ h,   bf16_t* __restrict__ hbf,
    const float* __restrict__ tW1, bf16_t* __restrict__ tW1T,
    const float* __restrict__ wW1, bf16_t* __restrict__ wW1T) {
  __shared__ float tile[32][33];
  int blk = blockIdx.x, tid = threadIdx.x;
  if (blk < 256) {                      // h: 262144 floats, float4-vectorized
    int gi = blk * 256 + tid;
    float4 v = ((const float4*)h)[gi];
    bf16x4 o = {(bf16_t)v.x, (bf16_t)v.y, (bf16_t)v.z, (bf16_t)v.w};
    ((bf16x4*)hbf)[gi] = o;
    return;
  }
  const float* in; bf16_t* out; int R = 1024, C = 512, t;
  if (blk < 768) { in = tW1; out = tW1T; t = blk - 256; }
  else           { in = wW1; out = wW1T; t = blk - 768; }
  int xt = C / 32;
  int c0 = (t % xt) * 32, r0 = (t / xt) * 32;
  int tx = tid & 31, ty = tid >> 5;
  for (int i = ty; i < 32; i += 8)
    tile[i][tx] = in[(size_t)(r0 + i) * C + c0 + tx];
  __syncthreads();
  for (int i = ty; i < 32; i += 8)
    out[(size_t)(c0 + i) * R + r0 + tx] = (bf16_t)tile[tx][i];
}

// ------- fused: 4x small GEMM (blocks 0..63) + wW2->fp8 ksl transpose (blocks 64..4159) ---
__global__ __launch_bounds__(256) void k_gemm4t(
    const bf16_t* __restrict__ A,
    const bf16_t* __restrict__ tW1T, const bf16_t* __restrict__ wW1T,
    float* __restrict__ Ut, float* __restrict__ Vt,
    float* __restrict__ Uw, float* __restrict__ Vw,
    const float* __restrict__ wW2, u8* __restrict__ w2t8)
{
  __shared__ __align__(16) char lds_raw[16384];
  const int tid = threadIdx.x;
  if (blockIdx.x >= 64) {
    float* tile = (float*)lds_raw;      // [32][33]
    int t = blockIdx.x - 64;            // 0..4095
    int c0 = (t % 256) * 32, r0 = (t / 256) * 32;
    int tx = tid & 31, ty = tid >> 5;
    for (int i = ty; i < 32; i += 8)
      tile[i * 33 + tx] = wW2[(size_t)(r0 + i) * 8192 + c0 + tx];
    __syncthreads();
    for (int i = ty; i < 32; i += 8) {
      int k = r0 + tx;
      int pos = (k >> 6) * 64 + ksl((k >> 3) & 7) * 8 + (k & 7);
      w2t8[(size_t)(c0 + i) * 512 + pos] = f2q(tile[tx * 33 + i]);
    }
    return;
  }
  bf16_t* As = (bf16_t*)lds_raw;
  bf16_t* Bs = (bf16_t*)(lds_raw + 8192);
  const int lane = tid & 63;
  const int wave = tid >> 6;
  const int wr = wave >> 1, wc = wave & 1;
  const int sel = blockIdx.x >> 4, sub = blockIdx.x & 15;
  const bf16_t* BT = (sel < 2 ? tW1T : wW1T) + (sel & 1) * 512;
  float* Cout = (sel == 0) ? Ut : (sel == 1) ? Vt : (sel == 2) ? Uw : Vw;
  const int m0 = (sub & 3) * 128, n0 = (sub >> 2) * 128;
  const int lda = 512, ldb = 1024, ldc = 512;

  const int rowS = tid >> 2;
  const int kS = (tid & 3) * 8;
  const bf16_t* gA0 = A + (size_t)(m0 + rowS) * lda + kS;
  const bf16_t* gA1 = A + (size_t)(m0 + rowS + 64) * lda + kS;
  const bf16_t* gB0 = BT + (size_t)(n0 + rowS) * ldb + kS;
  const bf16_t* gB1 = BT + (size_t)(n0 + rowS + 64) * ldb + kS;

  f32x4 acc[4][4] = {};
  const int aoff = (wr * 64 + (lane & 15)) * 32 + (lane >> 4) * 8;
  const int boff = (wc * 64 + (lane & 15)) * 32 + (lane >> 4) * 8;

  for (int k0 = 0; k0 < 512; k0 += 32) {
    __builtin_amdgcn_global_load_lds((const __attribute__((address_space(1))) void*)(gA0 + k0),
        (__attribute__((address_space(3))) void*)(As + wave * 512), 16, 0, 0);
    __builtin_amdgcn_global_load_lds((const __attribute__((address_space(1))) void*)(gA1 + k0),
        (__attribute__((address_space(3))) void*)(As + 2048 + wave * 512), 16, 0, 0);
    __builtin_amdgcn_global_load_lds((const __attribute__((address_space(1))) void*)(gB0 + k0),
        (__attribute__((address_space(3))) void*)(Bs + wave * 512), 16, 0, 0);
    __builtin_amdgcn_global_load_lds((const __attribute__((address_space(1))) void*)(gB1 + k0),
        (__attribute__((address_space(3))) void*)(Bs + 2048 + wave * 512), 16, 0, 0);
    __syncthreads();
    bf16x8 af[4], bfr[4];
    #pragma unroll
    for (int mf = 0; mf < 4; ++mf) af[mf] = *(const bf16x8*)&As[aoff + mf * 16 * 32];
    #pragma unroll
    for (int nf = 0; nf < 4; ++nf) bfr[nf] = *(const bf16x8*)&Bs[boff + nf * 16 * 32];
    #pragma unroll
    for (int mf = 0; mf < 4; ++mf)
      #pragma unroll
      for (int nf = 0; nf < 4; ++nf)
        acc[mf][nf] = __builtin_amdgcn_mfma_f32_16x16x32_bf16(af[mf], bfr[nf], acc[mf][nf], 0, 0, 0);
    __syncthreads();
  }
  #pragma unroll
  for (int mf = 0; mf < 4; ++mf)
    #pragma unroll
    for (int r2 = 0; r2 < 4; ++r2) {
      int grow = m0 + wr * 64 + mf * 16 + (lane >> 4) * 4 + r2;
      #pragma unroll
      for (int nf = 0; nf < 4; ++nf) {
        int gcol = n0 + wc * 64 + nf * 16 + (lane & 15);
        Cout[(size_t)grow * ldc + gcol] = acc[mf][nf][r2];
      }
    }
}

// ---------------- fp8 256x256-tile GEMM, 4-phase/iter (r12-measured loop & mapping) -------
// grid 2048; xcd=bid&7 owns m-tiles 8x..8x+7 (concurrent window 8m x 8n = 2MB, L2-clean).
// epilogue: LDS-reduce 4 wc-wave partials -> one plain store per row into psum[nt][row]
#define STAGEA(b, h, kt) do { \
  const u8* _s = A8 + (size_t)(m0 + (h)*128 + (tid>>2)) * 512 + (kt)*64 + csrc; \
  __builtin_amdgcn_global_load_lds((const __attribute__((address_space(1))) void*)_s, \
    (__attribute__((address_space(3))) void*)(As + (b)*16384 + (h)*8192 + (tid>>6)*1024), 16, 0, 0); \
} while(0)

#define STAGEB(b, h, kt) do { \
  const u8* _s = BT8 + (size_t)(n0 + (h)*128 + (tid>>2)) * 512 + (kt)*64 + csrc; \
  __builtin_amdgcn_global_load_lds((const __attribute__((address_space(1))) void*)_s, \
    (__attribute__((address_space(3))) void*)(Bs + (b)*16384 + (h)*8192 + (tid>>6)*1024), 16, 0, 0); \
} while(0)

#define LDA(b, mh) do { \
  _Pragma("unroll") \
  for (int _m = 0; _m < 4; ++_m) \
    afv[_m] = *(const i64x2*)(As + (b)*16384 + (mh)*8192 + ardE + _m*1024); \
} while(0)

#define LDB(b, nh) do { \
  _Pragma("unroll") \
  for (int _n = 0; _n < 2; ++_n) \
    bfv[nh][_n] = *(const i64x2*)(Bs + (b)*16384 + (nh)*8192 + brdE + _n*1024); \
} while(0)

#define MMA(mh, nh) do { \
  __builtin_amdgcn_s_setprio(1); \
  _Pragma("unroll") \
  for (int _m = 0; _m < 4; ++_m) \
    _Pragma("unroll") \
    for (int _n = 0; _n < 2; ++_n) { \
      acc[(mh)*4+_m][(nh)*2+_n] = __builtin_amdgcn_mfma_f32_16x16x32_fp8_fp8( \
          afv[_m][0], bfv[nh][_n][0], acc[(mh)*4+_m][(nh)*2+_n], 0, 0, 0); \
      acc[(mh)*4+_m][(nh)*2+_n] = __builtin_amdgcn_mfma_f32_16x16x32_fp8_fp8( \
          afv[_m][1], bfv[nh][_n][1], acc[(mh)*4+_m][(nh)*2+_n], 0, 0, 0); \
    } \
  __builtin_amdgcn_s_setprio(0); \
} while(0)

#define BARLG() do { __builtin_amdgcn_s_barrier(); \
  asm volatile("s_waitcnt lgkmcnt(0)" ::: "memory"); \
  __builtin_amdgcn_sched_barrier(0); } while(0)
#define ENDPH() __builtin_amdgcn_s_barrier()
#define CKPT() asm volatile("s_waitcnt vmcnt(2)" ::: "memory")

__global__ __launch_bounds__(512, 2) void k_gemm256(
    const u8* __restrict__ A8,
    const u8* __restrict__ BT8,
    const float* __restrict__ bias,
    float* __restrict__ psum)
{
  __shared__ __align__(16) u8 As[2 * 16384];   // [buf][half][128 rows][64B]
  __shared__ __align__(16) u8 Bs[2 * 16384];
  const int tid = threadIdx.x;
  const int l = tid & 63;
  const int wave = tid >> 6;
  const int wr = wave >> 2, wc = wave & 3;   // 2M x 4N waves

  const int xcd = blockIdx.x & 7, sub = blockIdx.x >> 3;   // sub 0..255
  const int mt = xcd * 8 + (sub & 7);
  const int nt = sub >> 3;
  const int m0 = mt * 256, n0 = nt * 256;

  const int csrc = (((tid & 3) ^ ((tid >> 3) & 3)) << 4);
  const int rsw = (((l >> 4) ^ ((l & 15) >> 1)) & 3) << 4;
  const int ardE = (wr * 64 + (l & 15)) * 64 + rsw;
  const int brdE = (wc * 32 + (l & 15)) * 64 + rsw;

  f32x4 acc[8][4] = {};
  i64x2 afv[4];
  i64x2 bfv[2][2];

  // prologue: K-tile 0 -> buf0 full (4 issues); K-tile 1 -> buf1.A0,B0 (2 issues)
  STAGEA(0, 0, 0); STAGEA(0, 1, 0); STAGEB(0, 0, 0); STAGEB(0, 1, 0);
  STAGEA(1, 0, 1); STAGEB(1, 0, 1);
  CKPT();
  __builtin_amdgcn_s_barrier();

  #pragma unroll 1
  for (int t = 0; t < 4; ++t) {
    int tA = 2 * t + 1;
    int tB = 2 * t + 2; if (tB > 7) tB = 7;
    int tC = 2 * t + 3; if (tC > 7) tC = 7;
    LDA(0, 0); LDB(0, 0); LDB(0, 1); STAGEA(1, 1, tA); STAGEB(1, 1, tA);
      BARLG(); MMA(0, 0); MMA(0, 1); ENDPH();
    LDA(0, 1);                       STAGEA(0, 0, tB); STAGEB(0, 0, tB);
      BARLG(); MMA(1, 0); MMA(1, 1); CKPT(); ENDPH();
    LDA(1, 0); LDB(1, 0); LDB(1, 1); STAGEA(0, 1, tB); STAGEB(0, 1, tB);
      BARLG(); MMA(0, 0); MMA(0, 1); ENDPH();
    LDA(1, 1);                       STAGEA(1, 0, tC); STAGEB(1, 0, tC);
      BARLG(); MMA(1, 0); MMA(1, 1); CKPT(); ENDPH();
  }

  // epilogue: per-wave 64-col exp-sums -> LDS reduce over wc -> one store per row
  __syncthreads();
  float b2v[4];
  #pragma unroll
  for (int nf = 0; nf < 4; ++nf)
    b2v[nf] = bias[n0 + (nf >> 1) * 128 + wc * 32 + (nf & 1) * 16 + (l & 15)];
  float* eL = (float*)As;   // [4 wc][256 rows]
  #pragma unroll
  for (int mf = 0; mf < 8; ++mf) {
    #pragma unroll
    for (int r2 = 0; r2 < 4; ++r2) {
      float s = 0.f;
      #pragma unroll
      for (int nf = 0; nf < 4; ++nf)
        s += __expf(acc[mf][nf][r2] + b2v[nf]);
      s += __shfl_xor(s, 1); s += __shfl_xor(s, 2);
      s += __shfl_xor(s, 4); s += __shfl_xor(s, 8);
      if ((l & 15) == 0)
        eL[wc * 256 + (mf >> 2) * 128 + wr * 64 + (mf & 3) * 16 + (l >> 4) * 4 + r2] = s;
    }
  }
  __syncthreads();
  if (tid < 256) {
    float v = eL[tid] + eL[256 + tid] + eL[512 + tid] + eL[768 + tid];
    psum[(size_t)nt * MPAD + m0 + tid] = v;
  }
}

// sumexp[row] = sum over 32 psum slots (coalesced); also zeroes out[0] for k_dp's atomics
__global__ __launch_bounds__(256) void k_red(const float* __restrict__ psum, float* __restrict__ sumexp,
                                             float* __restrict__ out) {
  if (blockIdx.x == 0 && threadIdx.x == 0) out[0] = 0.f;
  int r = blockIdx.x * 256 + threadIdx.x;
  float s = 0.f;
  #pragma unroll 8
  for (int sl = 0; sl < 32; ++sl) s += psum[(size_t)sl * MPAD + r];
  sumexp[r] = s;
}

// ---- fused act (+toklogit) & tnet-with-reuse kernel ----
__global__ __launch_bounds__(256) void k_actnet(
    const float* __restrict__ Uw, const float* __restrict__ Vw,
    const float* __restrict__ wb1, u8* __restrict__ act8,
    const u8* __restrict__ w2t8, const int* __restrict__ sent,
    const float* __restrict__ wb2, float* __restrict__ tok_logit,
    const float* __restrict__ Ut, const float* __restrict__ Vt,
    const float* __restrict__ tb1, const float* __restrict__ tW2,
    const float* __restrict__ tb2,
    float* __restrict__ sh_lp, float* __restrict__ re_lp)
{
  __shared__ float ldsf[8192];   // act: pd[512]; tnet: Us[8][512] + Vs[8][512]
  if (blockIdx.x < 2048) {
    float* pd = ldsf;
    int p = blockIdx.x;
    int iu = 0, ju = 0;
    bool real = (p < NPTOT);
    if (p < NPAIR) {
      int i = 0, base = 0;
      while (base + (62 - i) <= p) { base += 62 - i; ++i; }
      iu = i; ju = i + 1 + (p - base);
    }                                   // p==1953 -> (0,0)
    const int srow = (p < NPAIR) ? (ju + 1) : 1;
    for (int t = threadIdx.x; t < 512; t += 256) {   // 8 rows x 64 chunks
      int b = t >> 6, c = t & 63;
      int wpos = (c >> 3) * 64 + ksl(c & 7) * 8;     // ksl-permuted 8B slot
      u64 bytes = 0;
      float s = 0.f;
      if (real) {
        const float4* u4 = (const float4*)(Uw + (size_t)(iu * BB + b) * HH);
        const float4* v4 = (const float4*)(Vw + (size_t)(ju * BB + b) * HH);
        const float4* bb4 = (const float4*)wb1;
        int dw[2] = {0, 0};
        #pragma unroll
        for (int q = 0; q < 2; ++q) {
          float4 uu = u4[c * 2 + q], vv = v4[c * 2 + q], bb = bb4[c * 2 + q];
          float v0 = fmaxf(uu.x + vv.x + bb.x, 0.f);
          float v1 = fmaxf(uu.y + vv.y + bb.y, 0.f);
          float v2 = fmaxf(uu.z + vv.z + bb.z, 0.f);
          float v3 = fmaxf(uu.w + vv.w + bb.w, 0.f);
          dw[q] = __builtin_amdgcn_cvt_pk_fp8_f32(v0, v1, dw[q], false);
          dw[q] = __builtin_amdgcn_cvt_pk_fp8_f32(v2, v3, dw[q], true);
        }
        bytes = (u64)(u32)dw[0] | ((u64)(u32)dw[1] << 32);
        int tok = sent[srow * BB + b];
        u64 wv = *(const u64*)(w2t8 + (size_t)tok * 512 + wpos);  // same permuted slot
        int aw[2] = {(int)(u32)bytes, (int)(u32)(bytes >> 32)};
        int ww[2] = {(int)(u32)wv, (int)(u32)(wv >> 32)};
        #pragma unroll
        for (int q = 0; q < 2; ++q) {
          f32x2 alo = __builtin_amdgcn_cvt_pk_f32_fp8(aw[q], false);
          f32x2 ahi = __builtin_amdgcn_cvt_pk_f32_fp8(aw[q], true);
          f32x2 wlo = __builtin_amdgcn_cvt_pk_f32_fp8(ww[q], false);
          f32x2 whi = __builtin_amdgcn_cvt_pk_f32_fp8(ww[q], true);
          s += alo[0] * wlo[0] + alo[1] * wlo[1] + ahi[0] * whi[0] + ahi[1] * whi[1];
        }
      }
      *(u64*)(act8 + (size_t)(p * 8 + b) * 512 + wpos) = bytes;
      pd[t] = s;
    }
    __syncthreads();
    if (real) {
      int wv_ = threadIdx.x >> 6, ln = threadIdx.x & 63;
      #pragma unroll
      for (int rr = 0; rr < 2; ++rr) {
        int b = wv_ * 2 + rr;
        float s = pd[b * 64 + ln];
        #pragma unroll
        for (int off = 1; off < 64; off <<= 1) s += __shfl_xor(s, off);
        if (ln == 0) {
          int tok = sent[srow * BB + b];
          tok_logit[p * 8 + b] = s + wb2[tok];
        }
      }
    }
    return;
  }
  // ----- tnet branch: block = (b, group-pair ig<=jg); 8+8 rows cached in LDS -----
  int t = blockIdx.x - 2048;          // 0..287
  int b = t & 7, pr = t >> 3;         // pr 0..35
  int ig = 0, base = 0;
  while (base + (8 - ig) <= pr) { base += 8 - ig; ++ig; }
  int jg = ig + (pr - base);
  float* Us = ldsf;                   // [8][512]
  float* Vs = ldsf + 4096;            // [8][512]
  for (int q = threadIdx.x; q < 1024; q += 256) {
    int ii = q >> 7, cc = q & 127;
    ((float4*)Us)[ii * 128 + cc] = ((const float4*)(Ut + (size_t)((ig * 8 + ii) * BB + b) * HH))[cc];
    ((float4*)Vs)[ii * 128 + cc] = ((const float4*)(Vt + (size_t)((jg * 8 + ii) * BB + b) * HH))[cc];
  }
  __syncthreads();
  int lane = threadIdx.x & 63, wv_ = threadIdx.x >> 6;
  float b1r[8], w2r[8];
  #pragma unroll
  for (int k = 0; k < 8; ++k) { b1r[k] = tb1[lane + 64 * k]; w2r[k] = tW2[lane + 64 * k]; }
  for (int pp = wv_; pp < 64; pp += 4) {
    int ii = pp >> 3, jj = pp & 7;
    int i = ig * 8 + ii, j = jg * 8 + jj;
    float s = 0.f;
    #pragma unroll
    for (int k = 0; k < 8; ++k)
      s += fmaxf(Us[ii * 512 + lane + 64 * k] + Vs[jj * 512 + lane + 64 * k] + b1r[k], 0.f) * w2r[k];
    #pragma unroll
    for (int off = 1; off < 64; off <<= 1) s += __shfl_xor(s, off);
    if (lane == 0 && i < j) {
      float tv = s + tb2[0];
      re_lp[(i * 64 + j) * 8 + b] = logsig(tv);
      sh_lp[(i * 64 + j) * 8 + b] = logsig(-tv);
    }
  }
}

// inside DP: conflict-free tw/trT formulation (r13-measured); final via atomicAdd into out.
__global__ __launch_bounds__(1024) void k_dp(const float* __restrict__ sh_lp, const float* __restrict__ re_lp,
                                             const float* __restrict__ tok_logit, const float* __restrict__ sumexp,
                                             float* __restrict__ out) {
  int b = blockIdx.x;
  __shared__ float tw[4096];
  __shared__ float trT[4096];
  __shared__ float wplL[4096];
  __shared__ float relL[4096];
  int tid = threadIdx.x;
  for (int idx = tid; idx < 4096; idx += 1024) {
    int i = idx >> 6, j = idx & 63;
    float w = NEG;
    if (i < j && j <= 62) {
      int p = i * 62 - i * (i - 1) / 2 + (j - i - 1);
      int r = p * 8 + b;
      w = sh_lp[idx * 8 + b] + (tok_logit[r] - __logf(sumexp[r]));
    }
    wplL[idx] = w;
    relL[idx] = (i < j) ? re_lp[idx * 8 + b] : NEG;
  }
  __syncthreads();
  for (int idx = tid; idx < 4096; idx += 1024) {
    tw[idx] = NEG + wplL[idx];
    trT[idx] = NEG + relL[(idx & 63) * 64 + (idx >> 6)];
  }
  __syncthreads();
  if (tid == 0) {
    float v0 = tok_logit[NPAIR * 8 + b] - __logf(sumexp[NPAIR * 8 + b]);
    tw[1] = v0 + wplL[1];
    trT[1 * 64 + 0] = v0 + relL[0 * 64 + 1];
  }
  if (tid >= 1 && tid <= 62) {
    tw[tid * 64 + tid + 1] = wplL[tid * 64 + tid + 1];
    trT[(tid + 1) * 64 + tid] = relL[tid * 64 + tid + 1];
  }
  __syncthreads();
  int lane = tid & 63, wave = tid >> 6;   // 16 waves
  for (int g = 2; g <= 63; ++g) {
    int cnt = 64 - g;                     // i in [0, 63-g]
    if (g <= 17) {
      int seg = lane >> 4, sl = lane & 15;
      int i = wave * 4 + seg;
      if (i < cnt) {
        int m = sl + 1;
        int j = i + g, k = i + m;
        float sc = (m < g) ? tw[i * 64 + k] + trT[j * 64 + k] : NEG;
        float mx = sc;
        #pragma unroll
        for (int off = 1; off < 16; off <<= 1) mx = fmaxf(mx, __shfl_xor(mx, off));
        float e = (m < g) ? __expf(sc - mx) : 0.f;
        #pragma unroll
        for (int off = 1; off < 16; off <<= 1) e += __shfl_xor(e, off);
        if (sl == 0) {
          float val = __logf(e) + mx;
          tw[i * 64 + j] = val + wplL[i * 64 + j];
          trT[j * 64 + i] = val + relL[i * 64 + j];
        }
      }
    } else {
      for (int i = wave; i < cnt; i += 16) {
        int m = lane + 1;
        int j = i + g, k = i + m;
        float sc = (m < g) ? tw[i * 64 + k] + trT[j * 64 + k] : NEG;
        float mx = sc;
        #pragma unroll
        for (int off = 1; off < 64; off <<= 1) mx = fmaxf(mx, __shfl_xor(mx, off));
        float e = (m < g) ? __expf(sc - mx) : 0.f;
        #pragma unroll
        for (int off = 1; off < 64; off <<= 1) e += __shfl_xor(e, off);
        if (lane == 0) {
          float val = __logf(e) + mx;
          tw[i * 64 + j] = val + wplL[i * 64 + j];
          trT[j * 64 + i] = val + relL[i * 64 + j];
        }
      }
    }
    __syncthreads();
  }
  if (tid == 0) atomicAdd(out, -trT[63 * 64 + 0]);
}

extern "C" void kernel_launch(void* const* d_in, const int* in_sizes, int n_in,
                              void* d_out, int out_size, void* d_ws, size_t ws_size,
                              hipStream_t stream) {
  const float* h    = (const float*)d_in[0];
  const int*   sent = (const int*)d_in[1];
  const float* tW1  = (const float*)d_in[2];
  const float* tb1  = (const float*)d_in[3];
  const float* tW2  = (const float*)d_in[4];
  const float* tb2  = (const float*)d_in[5];
  const float* wW1  = (const float*)d_in[6];
  const float* wb1  = (const float*)d_in[7];
  const float* wW2  = (const float*)d_in[8];
  const float* wb2  = (const float*)d_in[9];
  float* out = (float*)d_out;

  char* ws = (char*)d_ws;
  size_t off = 0;
  auto alloc = [&](size_t bytes) { char* p = ws + off; off += (bytes + 255) & ~(size_t)255; return p; };
  bf16_t* hbf    = (bf16_t*)alloc((size_t)512 * 512 * 2);
  bf16_t* tW1T   = (bf16_t*)alloc((size_t)512 * 1024 * 2);
  bf16_t* wW1T   = (bf16_t*)alloc((size_t)512 * 1024 * 2);
  u8*     w2t8   = (u8*)alloc((size_t)VV * HH);
  float*  Ut     = (float*)alloc((size_t)512 * 512 * 4);
  float*  Vt     = (float*)alloc((size_t)512 * 512 * 4);
  float*  Uw     = (float*)alloc((size_t)512 * 512 * 4);
  float*  Vw     = (float*)alloc((size_t)512 * 512 * 4);
  u8*     act8   = (u8*)alloc((size_t)MPAD * HH);
  float*  psum   = (float*)alloc((size_t)32 * MPAD * 4);
  float*  sumexp = (float*)alloc((size_t)MPAD * 4);
  float*  tokl   = (float*)alloc((size_t)MPAD * 4);
  float*  shlp   = (float*)alloc((size_t)32768 * 4);
  float*  relp   = (float*)alloc((size_t)32768 * 4);

  k_prep<<<1280, 256, 0, stream>>>(h, hbf, tW1, tW1T, wW1, wW1T);
  k_gemm4t<<<4160, 256, 0, stream>>>(hbf, tW1T, wW1T, Ut, Vt, Uw, Vw, wW2, w2t8);
  k_actnet<<<2048 + 288, 256, 0, stream>>>(Uw, Vw, wb1, act8, w2t8, sent, wb2, tokl,
                                           Ut, Vt, tb1, tW2, tb2, shlp, relp);
  k_gemm256<<<2048, 512, 0, stream>>>(act8, w2t8, wb2, psum);
  k_red<<<MPAD / 256, 256, 0, stream>>>(psum, sumexp, out);
  k_dp<<<8, 1024, 0, stream>>>(shlp, relp, tokl, sumexp, out);
}